// Round 7
// baseline (564.561 us; speedup 1.0000x reference)
//
#include <hip/hip_runtime.h>
#include <stdint.h>

typedef __attribute__((ext_vector_type(8))) _Float16 half8;
typedef __attribute__((ext_vector_type(2))) __fp16 fp16x2;
typedef __attribute__((ext_vector_type(16))) float floatx16;

// features: [16, 512, 64, 64] fp32 -> feat[(b<<21) + (c<<12) + n], n = h*64+w
// memory:   [2048, 512] fp32 (K == V)
// out:      [16, 512, 64, 64] fp32
//
// Ktile (ws): A-frag layout for S^T=K*Q^T:  Ktile[(t*32+ks)*512 + L*8 + j]
//   = K[t*32 + (L&31)][ks*16 + (L>>5)*8 + j],  t=0..63 m-tiles, ks=0..31 c-chunks
// Vtile (ws): A-frag layout for O^T=V^T*P:   Vtile[((t*2+kv)*16+ct)*512 + L*8 + j]
//   = V[t*32 + kv*16 + (L>>5)*8 + j][ct*32 + (L&31)]

__global__ __launch_bounds__(256) void prep_kernel(const float* __restrict__ mem,
                                                   _Float16* __restrict__ Ktile,
                                                   _Float16* __restrict__ Vtile) {
    __shared__ _Float16 T[32 * 520];   // tile [m_local][c], stride 520
    const int t = blockIdx.x;          // m-tile 0..63
    const int tid = threadIdx.x;

    #pragma unroll
    for (int rep = 0; rep < 16; ++rep) {
        int idx = rep * 1024 + tid * 4;            // 0..16383
        float4 v = *(const float4*)&mem[(size_t)t * 16384 + idx];
        int row = idx >> 9, col = idx & 511;
        T[row * 520 + col + 0] = (_Float16)v.x;
        T[row * 520 + col + 1] = (_Float16)v.y;
        T[row * 520 + col + 2] = (_Float16)v.z;
        T[row * 520 + col + 3] = (_Float16)v.w;
    }
    __syncthreads();

    // Ktile: 32 ks * 64 lanes = 2048 groups of 8
    #pragma unroll
    for (int rep = 0; rep < 8; ++rep) {
        int u = rep * 256 + tid;
        int ks = u >> 6, L = u & 63;
        half8 kv = *(const half8*)&T[(L & 31) * 520 + ks * 16 + (L >> 5) * 8];
        *(half8*)&Ktile[(size_t)((t * 32 + ks) * 512 + L * 8)] = kv;
    }
    // Vtile: 2 kv * 16 ct * 64 lanes = 2048 groups of 8 (transposed reads)
    #pragma unroll
    for (int rep = 0; rep < 8; ++rep) {
        int u = rep * 256 + tid;
        int kv = u >> 10, ct = (u >> 6) & 15, L = u & 63;
        int c = ct * 32 + (L & 31);
        int mloc = kv * 16 + (L >> 5) * 8;
        half8 vv;
        #pragma unroll
        for (int j = 0; j < 8; ++j) vv[j] = T[(mloc + j) * 520 + c];
        *(half8*)&Vtile[(size_t)(((t * 2 + kv) * 16 + ct) * 512 + L * 8)] = vv;
    }
}

// dynamic LDS layout (163840 B = full 160 KiB, 1 block/CU):
//   [0,      65536)  Klds:  K double buffer, buf[t&1]; K(t+2) issued after B1(t)
//   [65536, 131072)  Vlds:  V double buffer, buf[t&1]; V(t) issued at Bstart(t),
//                           consumed by deferred PV(t) during tile t+1
//   [131072,163840)  Xc:    full-sp exchange, planes (q*8+w): [64] float4
#define SMEM_BYTES 163840

__device__ __forceinline__ void gload_lds16(const void* g, void* l) {
    __builtin_amdgcn_global_load_lds(
        (const __attribute__((address_space(1))) uint32_t*)g,
        (__attribute__((address_space(3))) uint32_t*)l,
        16, 0, 0);
}

__device__ __forceinline__ unsigned int pkrtz_u32(float a, float b) {
    fp16x2 hv = __builtin_amdgcn_cvt_pkrtz(a, b);
    return __builtin_bit_cast(unsigned int, hv);
}

// (x,y) = permlane32_swap(a,b): x = [a.lo | b.lo], y = [a.hi | b.hi]
__device__ __forceinline__ void plswap(unsigned int a, unsigned int b,
                                       unsigned int& x, unsigned int& y) {
    auto rr = __builtin_amdgcn_permlane32_swap((int)a, (int)b, false, false);
    x = (unsigned int)rr[0];
    y = (unsigned int)rr[1];
}

__global__ __launch_bounds__(512, 1) void attn_kernel(const float* __restrict__ feat,
                                                      const _Float16* __restrict__ Ktile,
                                                      const _Float16* __restrict__ Vtile,
                                                      float* __restrict__ out) {
    extern __shared__ __align__(16) char smem[];
    _Float16* Klds = (_Float16*)smem;                // + (buf)*16384 elements
    _Float16* Vlds = (_Float16*)(smem + 65536);      // + (buf)*16384 elements
    float4* Xc4 = (float4*)(smem + 131072);          // index (q*8 + w)*64 + L

    const int tid = (int)threadIdx.x;
    const int w  = tid >> 6;        // wave 0..7
    const int L  = tid & 63;
    const int r  = L & 31;          // query col within row-group
    const int h  = L >> 5;          // lane half
    const int p  = w & 1;           // c-split half
    const int rg = w >> 1;          // row-group 0..3

    const int r0 = (int)blockIdx.x * 128;
    const int b  = r0 >> 12;
    const int nb = r0 & 4095;

    // ---- issue K(0) -> buf0, K(1) -> buf1 (before Q loads: oldest in queue) ----
    #pragma unroll
    for (int rep = 0; rep < 4; ++rep) {
        const int off = ((rep * 8 + w) << 10);
        gload_lds16((const char*)Ktile + off + (L << 4), smem + off);
    }
    #pragma unroll
    for (int rep = 0; rep < 4; ++rep) {
        const int off = ((rep * 8 + w) << 10);
        gload_lds16((const char*)Ktile + 32768 + off + (L << 4), smem + 32768 + off);
    }

    // ---- Q B-fragments: qb[ks][j] = Q[r][p*256+ks*16+h*8+j]
    half8 qb[16];
    {
        const float* qp = feat + ((size_t)b << 21) + (size_t)(nb + rg * 32 + r);
        #pragma unroll
        for (int ks = 0; ks < 16; ++ks) {
            #pragma unroll
            for (int j = 0; j < 8; ++j) {
                qb[ks][j] = (_Float16)qp[(size_t)(p * 256 + ks * 16 + h * 8 + j) << 12];
            }
        }
    }

    floatx16 acc[8];
    #pragma unroll
    for (int i = 0; i < 8; ++i) acc[i] = (floatx16)0.0f;

    float mo = -1e30f, l = 0.0f;
    float aprev = 1.0f;
    bool  bprev = false;
    half8 pk0p = (half8)(_Float16)0.0f, pk1p = (half8)(_Float16)0.0f;

    for (int t = 0; t < 64; ++t) {
        // Bstart(t): counted wait — newest 4 outstanding = K(t+1) (stays in
        // flight); everything older (K(t), V(t-1)) has landed. Zero-stall gate.
        asm volatile("s_waitcnt vmcnt(4) lgkmcnt(0)" ::: "memory");
        __builtin_amdgcn_s_barrier();
        asm volatile("" ::: "memory");

        // ---- issue V(t) -> bufV[t&1] (consumed by PV(t) during tile t+1) ----
        {
            const char* g = (const char*)(Vtile + (size_t)t * 16384);
            char* lv = smem + 65536 + ((t & 1) << 15);
            #pragma unroll
            for (int rep = 0; rep < 4; ++rep) {
                const int off = ((rep * 8 + w) << 10);
                gload_lds16(g + off + (L << 4), lv + off);
            }
        }

        // ---- PHASE 1a: deferred rescale + PV(t-1) (bufV[(t-1)&1], landed) ----
        if (t) {
            if (__ballot(bprev)) {
                #pragma unroll
                for (int i = 0; i < 8; ++i) {
                    #pragma unroll
                    for (int k = 0; k < 16; ++k) acc[i][k] *= aprev;
                }
            }
            const _Float16* vb = Vlds + (size_t)(((t - 1) & 1) * 16384)
                                      + (p * 8) * 512 + L * 8;
            __builtin_amdgcn_s_setprio(1);
            #pragma unroll
            for (int ct = 0; ct < 8; ++ct) {
                half8 v0 = *(const half8*)(vb + (size_t)(ct * 512));
                half8 v1 = *(const half8*)(vb + (size_t)((16 + ct) * 512));
                acc[ct] = __builtin_amdgcn_mfma_f32_32x32x16_f16(v0, pk0p, acc[ct], 0, 0, 0);
                acc[ct] = __builtin_amdgcn_mfma_f32_32x32x16_f16(v1, pk1p, acc[ct], 0, 0, 0);
            }
            __builtin_amdgcn_s_setprio(0);
        }

        // ---- PHASE 1b: S^T over my c-half (16-MFMA chain), A from bufK[t&1] ----
        floatx16 s0 = (floatx16)0.0f;
        {
            const _Float16* kb = Klds + ((t & 1) << 14) + (p * 16) * 512 + L * 8;
            __builtin_amdgcn_s_setprio(1);
            #pragma unroll
            for (int ks = 0; ks < 16; ++ks) {
                half8 a0 = *(const half8*)(kb + (size_t)(ks * 512));
                s0 = __builtin_amdgcn_mfma_f32_32x32x16_f16(a0, qb[ks], s0, 0, 0, 0);
            }
            __builtin_amdgcn_s_setprio(0);
        }

        // ---- full-sp exchange write: 4 conflict-free float4 planes ----
        #pragma unroll
        for (int q = 0; q < 4; ++q) {
            Xc4[(q * 8 + w) * 64 + L] =
                make_float4(s0[4*q], s0[4*q+1], s0[4*q+2], s0[4*q+3]);
        }
        // B1: Xc visible; all waves done reading Klds buf[t&1]
        asm volatile("s_waitcnt lgkmcnt(0)" ::: "memory");
        __builtin_amdgcn_s_barrier();
        asm volatile("" ::: "memory");

        // ---- PHASE 2: issue K(t+2) -> bufK[t&1] (vacated; 1.5-tile lead) ----
        {
            const char* g = (const char*)(Ktile + (size_t)((t + 2) & 63) * 16384);
            char* lk = smem + ((t & 1) << 15);
            #pragma unroll
            for (int rep = 0; rep < 4; ++rep) {
                const int off = ((rep * 8 + w) << 10);
                gload_lds16(g + off + (L << 4), lk + off);
            }
        }

        // ---- combine: full so[16] (all 32 m for my h, this lane's query) ----
        float so[16];
        #pragma unroll
        for (int q = 0; q < 4; ++q) {
            float4 y = Xc4[(q * 8 + (w ^ 1)) * 64 + L];
            so[4*q+0] = s0[4*q+0] + y.x;
            so[4*q+1] = s0[4*q+1] + y.y;
            so[4*q+2] = s0[4*q+2] + y.z;
            so[4*q+3] = s0[4*q+3] + y.w;
        }

        // ---- softmax(t): tree row-max (depth 4), permlane halves-combine ----
        float red[8];
        #pragma unroll
        for (int k = 0; k < 8; ++k) red[k] = fmaxf(so[k], so[k + 8]);
        #pragma unroll
        for (int k = 0; k < 4; ++k) red[k] = fmaxf(red[k], red[k + 4]);
        float tm = fmaxf(fmaxf(red[0], red[1]), fmaxf(red[2], red[3]));
        {
            unsigned int x, y;
            plswap(__builtin_bit_cast(unsigned int, tm),
                   __builtin_bit_cast(unsigned int, tm), x, y);
            tm = fmaxf(__builtin_bit_cast(float, x), __builtin_bit_cast(float, y));
        }

        // defer-max (T13): only bump running max when growth > 8 -> rescale rare
        const bool bump = tm > mo + 8.0f;
        const float mn = bump ? tm : mo;
        const float alpha = bump ? __expf(mo - mn) : 1.0f;
        mo = mn;

        float pvE[16];
        #pragma unroll
        for (int k = 0; k < 16; ++k) pvE[k] = __expf(so[k] - mn);
        // tree row-sum (depth 4)
        float sr[8];
        #pragma unroll
        for (int k = 0; k < 8; ++k) sr[k] = pvE[k] + pvE[k + 8];
        #pragma unroll
        for (int k = 0; k < 4; ++k) sr[k] = sr[k] + sr[k + 4];
        float ts = (sr[0] + sr[1]) + (sr[2] + sr[3]);
        {
            unsigned int x, y;
            plswap(__builtin_bit_cast(unsigned int, ts),
                   __builtin_bit_cast(unsigned int, ts), x, y);
            ts = __builtin_bit_cast(float, x) + __builtin_bit_cast(float, y);
        }
        l = l * alpha + ts;

        // ---- pack P; assemble BOTH B-frags via 4 permlane32_swap (no DS) ----
        unsigned int wd[8];
        #pragma unroll
        for (int i = 0; i < 8; ++i) wd[i] = pkrtz_u32(pvE[2*i], pvE[2*i+1]);
        unsigned int x0, y0, x1, y1, x2, y2, x3, y3;
        plswap(wd[0], wd[2], x0, y0);
        plswap(wd[1], wd[3], x1, y1);
        plswap(wd[4], wd[6], x2, y2);
        plswap(wd[5], wd[7], x3, y3);
        const uint4 pk0u = make_uint4(x0, x1, y0, y1);
        const uint4 pk1u = make_uint4(x2, x3, y2, y3);
        pk0p = __builtin_bit_cast(half8, pk0u);
        pk1p = __builtin_bit_cast(half8, pk1u);
        aprev = alpha;
        bprev = bump;
    }

    // ---- tail: drain all DMA (V(63) + dummy K), then PV(63) from bufV[1] ----
    asm volatile("s_waitcnt vmcnt(0)" ::: "memory");
    __builtin_amdgcn_s_barrier();
    asm volatile("" ::: "memory");
    {
        if (__ballot(bprev)) {
            #pragma unroll
            for (int i = 0; i < 8; ++i) {
                #pragma unroll
                for (int k = 0; k < 16; ++k) acc[i][k] *= aprev;
            }
        }
        const _Float16* vb = Vlds + (size_t)16384 + (p * 8) * 512 + L * 8;
        #pragma unroll
        for (int ct = 0; ct < 8; ++ct) {
            half8 v0 = *(const half8*)(vb + (size_t)(ct * 512));
            half8 v1 = *(const half8*)(vb + (size_t)((16 + ct) * 512));
            acc[ct] = __builtin_amdgcn_mfma_f32_32x32x16_f16(v0, pk0p, acc[ct], 0, 0, 0);
            acc[ct] = __builtin_amdgcn_mfma_f32_32x32x16_f16(v1, pk1p, acc[ct], 0, 0, 0);
        }
    }

    // ---- epilogue: scale by 1/l, direct coalesced stores (col = n = lane) ----
    const float invl = 1.0f / l;
    const size_t ob = ((size_t)b << 21) + (size_t)(nb + rg * 32 + r);
    #pragma unroll
    for (int ct = 0; ct < 8; ++ct) {
        const int cbase = p * 256 + ct * 32 + 4 * h;
        #pragma unroll
        for (int k = 0; k < 16; ++k) {
            int cl = (k & 3) + 8 * (k >> 2);
            out[ob + ((size_t)(cbase + cl) << 12)] = acc[ct][k] * invl;
        }
    }
}

extern "C" void kernel_launch(void* const* d_in, const int* in_sizes, int n_in,
                              void* d_out, int out_size, void* d_ws, size_t ws_size,
                              hipStream_t stream) {
    (void)in_sizes; (void)n_in; (void)out_size; (void)ws_size;
    const float* feat = (const float*)d_in[0];
    const float* mem  = (const float*)d_in[1];
    float* outp = (float*)d_out;
    _Float16* Ktile = (_Float16*)d_ws;                        // 2 MB
    _Float16* Vtile = Ktile + (size_t)2048 * 512;             // 2 MB

    static bool attr_done = false;
    if (!attr_done) {
        (void)hipFuncSetAttribute(reinterpret_cast<const void*>(attn_kernel),
                                  hipFuncAttributeMaxDynamicSharedMemorySize, SMEM_BYTES);
        attr_done = true;
    }

    hipLaunchKernelGGL(prep_kernel, dim3(64), dim3(256), 0, stream, mem, Ktile, Vtile);
    hipLaunchKernelGGL(attn_kernel, dim3(512), dim3(512), SMEM_BYTES, stream,
                       feat, Ktile, Vtile, outp);
}

// Round 8
// 536.411 us; speedup vs baseline: 1.0525x; 1.0525x over previous
//
#include <hip/hip_runtime.h>
#include <stdint.h>

typedef __attribute__((ext_vector_type(8))) _Float16 half8;
typedef __attribute__((ext_vector_type(2))) __fp16 fp16x2;
typedef __attribute__((ext_vector_type(16))) float floatx16;

// features: [16, 512, 64, 64] fp32 -> feat[(b<<21) + (c<<12) + n], n = h*64+w
// memory:   [2048, 512] fp32 (K == V)
// out:      [16, 512, 64, 64] fp32
//
// Ktile (ws): A-frag layout for S^T=K*Q^T:  Ktile[(t*32+ks)*512 + L*8 + j]
//   = K[t*32 + (L&31)][ks*16 + (L>>5)*8 + j],  t=0..63 m-tiles, ks=0..31 c-chunks
// Vtile (ws): A-frag layout for O^T=V^T*P:   Vtile[((t*2+kv)*16+ct)*512 + L*8 + j]
//   = V[t*32 + kv*16 + (L>>5)*8 + j][ct*32 + (L&31)]

__global__ __launch_bounds__(256) void prep_kernel(const float* __restrict__ mem,
                                                   _Float16* __restrict__ Ktile,
                                                   _Float16* __restrict__ Vtile) {
    __shared__ _Float16 T[32 * 520];   // tile [m_local][c], stride 520
    const int t = blockIdx.x;          // m-tile 0..63
    const int tid = threadIdx.x;

    #pragma unroll
    for (int rep = 0; rep < 16; ++rep) {
        int idx = rep * 1024 + tid * 4;            // 0..16383
        float4 v = *(const float4*)&mem[(size_t)t * 16384 + idx];
        int row = idx >> 9, col = idx & 511;
        T[row * 520 + col + 0] = (_Float16)v.x;
        T[row * 520 + col + 1] = (_Float16)v.y;
        T[row * 520 + col + 2] = (_Float16)v.z;
        T[row * 520 + col + 3] = (_Float16)v.w;
    }
    __syncthreads();

    // Ktile: 32 ks * 64 lanes = 2048 groups of 8
    #pragma unroll
    for (int rep = 0; rep < 8; ++rep) {
        int u = rep * 256 + tid;
        int ks = u >> 6, L = u & 63;
        half8 kv = *(const half8*)&T[(L & 31) * 520 + ks * 16 + (L >> 5) * 8];
        *(half8*)&Ktile[(size_t)((t * 32 + ks) * 512 + L * 8)] = kv;
    }
    // Vtile: 2 kv * 16 ct * 64 lanes = 2048 groups of 8 (transposed reads)
    #pragma unroll
    for (int rep = 0; rep < 8; ++rep) {
        int u = rep * 256 + tid;
        int kv = u >> 10, ct = (u >> 6) & 15, L = u & 63;
        int c = ct * 32 + (L & 31);
        int mloc = kv * 16 + (L >> 5) * 8;
        half8 vv;
        #pragma unroll
        for (int j = 0; j < 8; ++j) vv[j] = T[(mloc + j) * 520 + c];
        *(half8*)&Vtile[(size_t)(((t * 2 + kv) * 16 + ct) * 512 + L * 8)] = vv;
    }
}

// dynamic LDS layout (163840 B = full 160 KiB, 1 block/CU):
//   [0,      65536)  Klds:  K double buffer, buf[t&1]; K(t+2) issued after B1(t)
//   [65536, 131072)  Vlds:  V double buffer, buf[t&1]; V(t) issued at Bstart(t),
//                           consumed by deferred PV(t) during tile t+1
//   [131072,163840)  Xc:    full-sp exchange, planes (q*8+w): [64] float4
#define SMEM_BYTES 163840

__device__ __forceinline__ void gload_lds16(const void* g, void* l) {
    __builtin_amdgcn_global_load_lds(
        (const __attribute__((address_space(1))) uint32_t*)g,
        (__attribute__((address_space(3))) uint32_t*)l,
        16, 0, 0);
}

__device__ __forceinline__ unsigned int pkrtz_u32(float a, float b) {
    fp16x2 hv = __builtin_amdgcn_cvt_pkrtz(a, b);
    return __builtin_bit_cast(unsigned int, hv);
}

// (x,y) = permlane32_swap(a,b): x = [a.lo | b.lo], y = [a.hi | b.hi]
__device__ __forceinline__ void plswap(unsigned int a, unsigned int b,
                                       unsigned int& x, unsigned int& y) {
    auto rr = __builtin_amdgcn_permlane32_swap((int)a, (int)b, false, false);
    x = (unsigned int)rr[0];
    y = (unsigned int)rr[1];
}

__global__ __launch_bounds__(512, 1) void attn_kernel(const float* __restrict__ feat,
                                                      const _Float16* __restrict__ Ktile,
                                                      const _Float16* __restrict__ Vtile,
                                                      float* __restrict__ out) {
    extern __shared__ __align__(16) char smem[];
    _Float16* Klds = (_Float16*)smem;                // + (buf)*16384 elements
    _Float16* Vlds = (_Float16*)(smem + 65536);      // + (buf)*16384 elements
    float4* Xc4 = (float4*)(smem + 131072);          // index (q*8 + w)*64 + L

    const int tid = (int)threadIdx.x;
    const int w  = tid >> 6;        // wave 0..7
    const int L  = tid & 63;
    const int r  = L & 31;          // query col within row-group
    const int h  = L >> 5;          // lane half
    const int p  = w & 1;           // c-split half
    const int rg = w >> 1;          // row-group 0..3

    const int r0 = (int)blockIdx.x * 128;
    const int b  = r0 >> 12;
    const int nb = r0 & 4095;

    // ---- issue K(0) -> buf0, K(1) -> buf1 (before Q loads: oldest in queue) ----
    #pragma unroll
    for (int rep = 0; rep < 4; ++rep) {
        const int off = ((rep * 8 + w) << 10);
        gload_lds16((const char*)Ktile + off + (L << 4), smem + off);
    }
    #pragma unroll
    for (int rep = 0; rep < 4; ++rep) {
        const int off = ((rep * 8 + w) << 10);
        gload_lds16((const char*)Ktile + 32768 + off + (L << 4), smem + 32768 + off);
    }

    // ---- Q B-fragments: qb[ks][j] = Q[r][p*256+ks*16+h*8+j]
    half8 qb[16];
    {
        const float* qp = feat + ((size_t)b << 21) + (size_t)(nb + rg * 32 + r);
        #pragma unroll
        for (int ks = 0; ks < 16; ++ks) {
            #pragma unroll
            for (int j = 0; j < 8; ++j) {
                qb[ks][j] = (_Float16)qp[(size_t)(p * 256 + ks * 16 + h * 8 + j) << 12];
            }
        }
    }

    floatx16 acc[8];
    #pragma unroll
    for (int i = 0; i < 8; ++i) acc[i] = (floatx16)0.0f;

    float mo = -1e30f, l = 0.0f;
    float aprev = 1.0f;
    bool  bprev = false;
    half8 pk0p = (half8)(_Float16)0.0f, pk1p = (half8)(_Float16)0.0f;

    for (int t = 0; t < 64; ++t) {
        // Bstart(t): counted wait — newest 4 outstanding = K(t+1) (stays in
        // flight); everything older (K(t), V(t-1)) has landed. Zero-stall gate.
        asm volatile("s_waitcnt vmcnt(4) lgkmcnt(0)" ::: "memory");
        __builtin_amdgcn_s_barrier();
        asm volatile("" ::: "memory");

        // ---- issue V(t) -> bufV[t&1] (consumed by PV(t) during tile t+1) ----
        {
            const char* g = (const char*)(Vtile + (size_t)t * 16384);
            char* lv = smem + 65536 + ((t & 1) << 15);
            #pragma unroll
            for (int rep = 0; rep < 4; ++rep) {
                const int off = ((rep * 8 + w) << 10);
                gload_lds16(g + off + (L << 4), lv + off);
            }
        }

        // ---- S^T over my c-half: DUAL 8-MFMA chains (half the dep depth) ----
        floatx16 s0 = (floatx16)0.0f, s1 = (floatx16)0.0f;
        {
            const _Float16* kb = Klds + ((t & 1) << 14) + (p * 16) * 512 + L * 8;
            __builtin_amdgcn_s_setprio(1);
            #pragma unroll
            for (int ksl = 0; ksl < 16; ksl += 2) {
                half8 a0 = *(const half8*)(kb + (size_t)(ksl * 512));
                half8 a1 = *(const half8*)(kb + (size_t)((ksl + 1) * 512));
                s0 = __builtin_amdgcn_mfma_f32_32x32x16_f16(a0, qb[ksl], s0, 0, 0, 0);
                s1 = __builtin_amdgcn_mfma_f32_32x32x16_f16(a1, qb[ksl + 1], s1, 0, 0, 0);
            }
            __builtin_amdgcn_s_setprio(0);
        }
        float sp[16];
        #pragma unroll
        for (int k = 0; k < 16; ++k) sp[k] = s0[k] + s1[k];

        // ---- full-sp exchange write: 4 conflict-free float4 planes ----
        #pragma unroll
        for (int q = 0; q < 4; ++q) {
            Xc4[(q * 8 + w) * 64 + L] =
                make_float4(sp[4*q], sp[4*q+1], sp[4*q+2], sp[4*q+3]);
        }
        // B1: Xc visible; all waves done reading Klds buf[t&1]
        asm volatile("s_waitcnt lgkmcnt(0)" ::: "memory");
        __builtin_amdgcn_s_barrier();
        asm volatile("" ::: "memory");

        // ---- combine FIRST (start Xc read latency right after B1) ----
        float so[16];
        #pragma unroll
        for (int q = 0; q < 4; ++q) {
            float4 y = Xc4[(q * 8 + (w ^ 1)) * 64 + L];
            so[4*q+0] = sp[4*q+0] + y.x;
            so[4*q+1] = sp[4*q+1] + y.y;
            so[4*q+2] = sp[4*q+2] + y.z;
            so[4*q+3] = sp[4*q+3] + y.w;
        }

        // ---- issue K(t+2) -> bufK[t&1] (vacated; 1.5-tile lead).
        //      t=62/63 issue dummy K(0)/K(1) — never read; keeps vmcnt exact. ----
        {
            const char* g = (const char*)(Ktile + (size_t)((t + 2) & 63) * 16384);
            char* lk = smem + ((t & 1) << 15);
            #pragma unroll
            for (int rep = 0; rep < 4; ++rep) {
                const int off = ((rep * 8 + w) << 10);
                gload_lds16(g + off + (L << 4), lk + off);
            }
        }

        // ---- deferred rescale + PV(t-1): reads bufV[(t-1)&1] (landed+synced);
        //      independent of softmax(t) below -> MFMA pipe covers the VALU ----
        if (t) {
            if (__ballot(bprev)) {
                #pragma unroll
                for (int i = 0; i < 8; ++i) {
                    #pragma unroll
                    for (int k = 0; k < 16; ++k) acc[i][k] *= aprev;
                }
            }
            const _Float16* vb = Vlds + (size_t)(((t - 1) & 1) * 16384)
                                      + (p * 8) * 512 + L * 8;
            __builtin_amdgcn_s_setprio(1);
            #pragma unroll
            for (int ct = 0; ct < 8; ++ct) {
                half8 v0 = *(const half8*)(vb + (size_t)(ct * 512));
                half8 v1 = *(const half8*)(vb + (size_t)((16 + ct) * 512));
                acc[ct] = __builtin_amdgcn_mfma_f32_32x32x16_f16(v0, pk0p, acc[ct], 0, 0, 0);
                acc[ct] = __builtin_amdgcn_mfma_f32_32x32x16_f16(v1, pk1p, acc[ct], 0, 0, 0);
            }
            __builtin_amdgcn_s_setprio(0);
        }

        // ---- softmax(t): tree row-max (depth 4), permlane halves-combine ----
        float red[8];
        #pragma unroll
        for (int k = 0; k < 8; ++k) red[k] = fmaxf(so[k], so[k + 8]);
        #pragma unroll
        for (int k = 0; k < 4; ++k) red[k] = fmaxf(red[k], red[k + 4]);
        float tm = fmaxf(fmaxf(red[0], red[1]), fmaxf(red[2], red[3]));
        {
            unsigned int x, y;
            plswap(__builtin_bit_cast(unsigned int, tm),
                   __builtin_bit_cast(unsigned int, tm), x, y);
            tm = fmaxf(__builtin_bit_cast(float, x), __builtin_bit_cast(float, y));
        }

        // defer-max (T13): only bump running max when growth > 8 -> rescale rare
        const bool bump = tm > mo + 8.0f;
        const float mn = bump ? tm : mo;
        const float alpha = bump ? __expf(mo - mn) : 1.0f;
        mo = mn;

        float pvE[16];
        #pragma unroll
        for (int k = 0; k < 16; ++k) pvE[k] = __expf(so[k] - mn);
        // tree row-sum (depth 4)
        float sr[8];
        #pragma unroll
        for (int k = 0; k < 8; ++k) sr[k] = pvE[k] + pvE[k + 8];
        #pragma unroll
        for (int k = 0; k < 4; ++k) sr[k] = sr[k] + sr[k + 4];
        float ts = (sr[0] + sr[1]) + (sr[2] + sr[3]);
        {
            unsigned int x, y;
            plswap(__builtin_bit_cast(unsigned int, ts),
                   __builtin_bit_cast(unsigned int, ts), x, y);
            ts = __builtin_bit_cast(float, x) + __builtin_bit_cast(float, y);
        }
        l = l * alpha + ts;

        // ---- pack P; assemble BOTH B-frags via 4 permlane32_swap (no DS) ----
        unsigned int wd[8];
        #pragma unroll
        for (int i = 0; i < 8; ++i) wd[i] = pkrtz_u32(pvE[2*i], pvE[2*i+1]);
        unsigned int x0, y0, x1, y1, x2, y2, x3, y3;
        plswap(wd[0], wd[2], x0, y0);
        plswap(wd[1], wd[3], x1, y1);
        plswap(wd[4], wd[6], x2, y2);
        plswap(wd[5], wd[7], x3, y3);
        const uint4 pk0u = make_uint4(x0, x1, y0, y1);
        const uint4 pk1u = make_uint4(x2, x3, y2, y3);
        pk0p = __builtin_bit_cast(half8, pk0u);
        pk1p = __builtin_bit_cast(half8, pk1u);
        aprev = alpha;
        bprev = bump;
    }

    // ---- tail: drain all DMA (V(63) + dummy K), then PV(63) from bufV[1] ----
    asm volatile("s_waitcnt vmcnt(0)" ::: "memory");
    __builtin_amdgcn_s_barrier();
    asm volatile("" ::: "memory");
    {
        if (__ballot(bprev)) {
            #pragma unroll
            for (int i = 0; i < 8; ++i) {
                #pragma unroll
                for (int k = 0; k < 16; ++k) acc[i][k] *= aprev;
            }
        }
        const _Float16* vb = Vlds + (size_t)16384 + (p * 8) * 512 + L * 8;
        #pragma unroll
        for (int ct = 0; ct < 8; ++ct) {
            half8 v0 = *(const half8*)(vb + (size_t)(ct * 512));
            half8 v1 = *(const half8*)(vb + (size_t)((16 + ct) * 512));
            acc[ct] = __builtin_amdgcn_mfma_f32_32x32x16_f16(v0, pk0p, acc[ct], 0, 0, 0);
            acc[ct] = __builtin_amdgcn_mfma_f32_32x32x16_f16(v1, pk1p, acc[ct], 0, 0, 0);
        }
    }

    // ---- epilogue: scale by 1/l, direct coalesced stores (col = n = lane) ----
    const float invl = 1.0f / l;
    const size_t ob = ((size_t)b << 21) + (size_t)(nb + rg * 32 + r);
    #pragma unroll
    for (int ct = 0; ct < 8; ++ct) {
        const int cbase = p * 256 + ct * 32 + 4 * h;
        #pragma unroll
        for (int k = 0; k < 16; ++k) {
            int cl = (k & 3) + 8 * (k >> 2);
            out[ob + ((size_t)(cbase + cl) << 12)] = acc[ct][k] * invl;
        }
    }
}

extern "C" void kernel_launch(void* const* d_in, const int* in_sizes, int n_in,
                              void* d_out, int out_size, void* d_ws, size_t ws_size,
                              hipStream_t stream) {
    (void)in_sizes; (void)n_in; (void)out_size; (void)ws_size;
    const float* feat = (const float*)d_in[0];
    const float* mem  = (const float*)d_in[1];
    float* outp = (float*)d_out;
    _Float16* Ktile = (_Float16*)d_ws;                        // 2 MB
    _Float16* Vtile = Ktile + (size_t)2048 * 512;             // 2 MB

    static bool attr_done = false;
    if (!attr_done) {
        (void)hipFuncSetAttribute(reinterpret_cast<const void*>(attn_kernel),
                                  hipFuncAttributeMaxDynamicSharedMemorySize, SMEM_BYTES);
        attr_done = true;
    }

    hipLaunchKernelGGL(prep_kernel, dim3(64), dim3(256), 0, stream, mem, Ktile, Vtile);
    hipLaunchKernelGGL(attn_kernel, dim3(512), dim3(512), SMEM_BYTES, stream,
                       feat, Ktile, Vtile, outp);
}

// Round 9
// 518.727 us; speedup vs baseline: 1.0884x; 1.0341x over previous
//
#include <hip/hip_runtime.h>
#include <stdint.h>

typedef __attribute__((ext_vector_type(8))) _Float16 half8;
typedef __attribute__((ext_vector_type(2))) __fp16 fp16x2;
typedef __attribute__((ext_vector_type(16))) float floatx16;

// features: [16, 512, 64, 64] fp32 -> feat[(b<<21) + (c<<12) + n], n = h*64+w
// memory:   [2048, 512] fp32 (K == V)
// out:      [16, 512, 64, 64] fp32
//
// Ktile (ws): A-frag layout for S^T=K*Q^T:  Ktile[(t*32+ks)*512 + L*8 + j]
//   = K[t*32 + (L&31)][ks*16 + (L>>5)*8 + j],  t=0..63 m-tiles, ks=0..31 c-chunks
// Vtile (ws): A-frag layout for O^T=V^T*P:   Vtile[((t*2+kv)*16+ct)*512 + L*8 + j]
//   = V[t*32 + kv*16 + (L>>5)*8 + j][ct*32 + (L&31)]

__global__ __launch_bounds__(256) void prep_kernel(const float* __restrict__ mem,
                                                   _Float16* __restrict__ Ktile,
                                                   _Float16* __restrict__ Vtile) {
    __shared__ _Float16 T[32 * 520];   // tile [m_local][c], stride 520
    const int t = blockIdx.x;          // m-tile 0..63
    const int tid = threadIdx.x;

    #pragma unroll
    for (int rep = 0; rep < 16; ++rep) {
        int idx = rep * 1024 + tid * 4;            // 0..16383
        float4 v = *(const float4*)&mem[(size_t)t * 16384 + idx];
        int row = idx >> 9, col = idx & 511;
        T[row * 520 + col + 0] = (_Float16)v.x;
        T[row * 520 + col + 1] = (_Float16)v.y;
        T[row * 520 + col + 2] = (_Float16)v.z;
        T[row * 520 + col + 3] = (_Float16)v.w;
    }
    __syncthreads();

    // Ktile: 32 ks * 64 lanes = 2048 groups of 8
    #pragma unroll
    for (int rep = 0; rep < 8; ++rep) {
        int u = rep * 256 + tid;
        int ks = u >> 6, L = u & 63;
        half8 kv = *(const half8*)&T[(L & 31) * 520 + ks * 16 + (L >> 5) * 8];
        *(half8*)&Ktile[(size_t)((t * 32 + ks) * 512 + L * 8)] = kv;
    }
    // Vtile: 2 kv * 16 ct * 64 lanes = 2048 groups of 8 (transposed reads)
    #pragma unroll
    for (int rep = 0; rep < 8; ++rep) {
        int u = rep * 256 + tid;
        int kv = u >> 10, ct = (u >> 6) & 15, L = u & 63;
        int c = ct * 32 + (L & 31);
        int mloc = kv * 16 + (L >> 5) * 8;
        half8 vv;
        #pragma unroll
        for (int j = 0; j < 8; ++j) vv[j] = T[(mloc + j) * 520 + c];
        *(half8*)&Vtile[(size_t)(((t * 2 + kv) * 16 + ct) * 512 + L * 8)] = vv;
    }
}

// dynamic LDS layout (163840 B = full 160 KiB, 1 block/CU):
//   [0,      65536)  Klds:  K double buffer, buf[t&1]; K(t+2) issued after B1(t)
//   [65536, 131072)  Vlds:  V double buffer, buf[t&1]; V(t) issued at Bstart(t),
//                           consumed by deferred PV(t) during tile t+1
//   [131072,163840)  Xc:    full-sp exchange, planes (q*8+w): [64] float4
#define SMEM_BYTES 163840

__device__ __forceinline__ void gload_lds16(const void* g, void* l) {
    __builtin_amdgcn_global_load_lds(
        (const __attribute__((address_space(1))) uint32_t*)g,
        (__attribute__((address_space(3))) uint32_t*)l,
        16, 0, 0);
}

__device__ __forceinline__ unsigned int pkrtz_u32(float a, float b) {
    fp16x2 hv = __builtin_amdgcn_cvt_pkrtz(a, b);
    return __builtin_bit_cast(unsigned int, hv);
}

// (x,y) = permlane32_swap(a,b): x = [a.lo | b.lo], y = [a.hi | b.hi]
__device__ __forceinline__ void plswap(unsigned int a, unsigned int b,
                                       unsigned int& x, unsigned int& y) {
    auto rr = __builtin_amdgcn_permlane32_swap((int)a, (int)b, false, false);
    x = (unsigned int)rr[0];
    y = (unsigned int)rr[1];
}

__global__ __launch_bounds__(512, 1) void attn_kernel(const float* __restrict__ feat,
                                                      const _Float16* __restrict__ Ktile,
                                                      const _Float16* __restrict__ Vtile,
                                                      float* __restrict__ out) {
    extern __shared__ __align__(16) char smem[];
    _Float16* Klds = (_Float16*)smem;                // + (buf)*16384 elements
    _Float16* Vlds = (_Float16*)(smem + 65536);      // + (buf)*16384 elements
    float4* Xc4 = (float4*)(smem + 131072);          // index (q*8 + w)*64 + L

    const int tid = (int)threadIdx.x;
    const int w  = tid >> 6;        // wave 0..7
    const int L  = tid & 63;
    const int r  = L & 31;          // query col within row-group
    const int h  = L >> 5;          // lane half
    const int p  = w & 1;           // c-split half
    const int rg = w >> 1;          // row-group 0..3

    const int r0 = (int)blockIdx.x * 128;
    const int b  = r0 >> 12;
    const int nb = r0 & 4095;

    // ---- issue K(0) -> buf0, K(1) -> buf1 (before Q loads: oldest in queue) ----
    #pragma unroll
    for (int rep = 0; rep < 4; ++rep) {
        const int off = ((rep * 8 + w) << 10);
        gload_lds16((const char*)Ktile + off + (L << 4), smem + off);
    }
    #pragma unroll
    for (int rep = 0; rep < 4; ++rep) {
        const int off = ((rep * 8 + w) << 10);
        gload_lds16((const char*)Ktile + 32768 + off + (L << 4), smem + 32768 + off);
    }

    // ---- Q B-fragments: qb[ks][j] = Q[r][p*256+ks*16+h*8+j]
    half8 qb[16];
    {
        const float* qp = feat + ((size_t)b << 21) + (size_t)(nb + rg * 32 + r);
        #pragma unroll
        for (int ks = 0; ks < 16; ++ks) {
            #pragma unroll
            for (int j = 0; j < 8; ++j) {
                qb[ks][j] = (_Float16)qp[(size_t)(p * 256 + ks * 16 + h * 8 + j) << 12];
            }
        }
    }

    floatx16 acc[8];
    #pragma unroll
    for (int i = 0; i < 8; ++i) acc[i] = (floatx16)0.0f;

    float mo = -1e30f, l = 0.0f;
    float aprev = 1.0f;
    bool  bprev = false;
    half8 pk0p = (half8)(_Float16)0.0f, pk1p = (half8)(_Float16)0.0f;

    for (int t = 0; t < 64; ++t) {
        // Bstart(t): counted wait — newest 4 outstanding = K(t+1) (stays in
        // flight); everything older (K(t), V(t-1)) has landed. Zero-stall gate.
        asm volatile("s_waitcnt vmcnt(4) lgkmcnt(0)" ::: "memory");
        __builtin_amdgcn_s_barrier();
        asm volatile("" ::: "memory");

        // ---- issue V(t) -> bufV[t&1] (consumed by PV(t) during tile t+1) ----
        {
            const char* g = (const char*)(Vtile + (size_t)t * 16384);
            char* lv = smem + 65536 + ((t & 1) << 15);
            #pragma unroll
            for (int rep = 0; rep < 4; ++rep) {
                const int off = ((rep * 8 + w) << 10);
                gload_lds16(g + off + (L << 4), lv + off);
            }
        }

        // ---- S^T over my c-half: single 16-MFMA accumulate chain, A from LDS ----
        floatx16 s0 = (floatx16)0.0f;
        {
            const _Float16* kb = Klds + ((t & 1) << 14) + (p * 16) * 512 + L * 8;
            __builtin_amdgcn_s_setprio(1);
            #pragma unroll
            for (int ks = 0; ks < 16; ++ks) {
                half8 a0 = *(const half8*)(kb + (size_t)(ks * 512));
                s0 = __builtin_amdgcn_mfma_f32_32x32x16_f16(a0, qb[ks], s0, 0, 0, 0);
            }
            __builtin_amdgcn_s_setprio(0);
        }

        // ---- full-sp exchange write: 4 conflict-free float4 planes ----
        #pragma unroll
        for (int q = 0; q < 4; ++q) {
            Xc4[(q * 8 + w) * 64 + L] =
                make_float4(s0[4*q], s0[4*q+1], s0[4*q+2], s0[4*q+3]);
        }
        // B1: Xc visible; all waves done reading Klds buf[t&1]
        asm volatile("s_waitcnt lgkmcnt(0)" ::: "memory");
        __builtin_amdgcn_s_barrier();
        asm volatile("" ::: "memory");

        // ---- issue K(t+2) -> bufK[t&1] (vacated; 1.5-tile lead).
        //      t=62/63 issue dummy K(0)/K(1) — never read; keeps vmcnt exact. ----
        {
            const char* g = (const char*)(Ktile + (size_t)((t + 2) & 63) * 16384);
            char* lk = smem + ((t & 1) << 15);
            #pragma unroll
            for (int rep = 0; rep < 4; ++rep) {
                const int off = ((rep * 8 + w) << 10);
                gload_lds16(g + off + (L << 4), lk + off);
            }
        }

        // ---- combine: full so[16] (all 32 m for my h, this lane's query) ----
        float so[16];
        #pragma unroll
        for (int q = 0; q < 4; ++q) {
            float4 y = Xc4[(q * 8 + (w ^ 1)) * 64 + L];
            so[4*q+0] = s0[4*q+0] + y.x;
            so[4*q+1] = s0[4*q+1] + y.y;
            so[4*q+2] = s0[4*q+2] + y.z;
            so[4*q+3] = s0[4*q+3] + y.w;
        }

        // ---- deferred rescale + PV(t-1): reads bufV[(t-1)&1] (landed+synced);
        //      independent of softmax(t) below -> MFMA pipe covers the VALU ----
        if (t) {
            if (__ballot(bprev)) {
                #pragma unroll
                for (int i = 0; i < 8; ++i) {
                    #pragma unroll
                    for (int k = 0; k < 16; ++k) acc[i][k] *= aprev;
                }
            }
            const _Float16* vb = Vlds + (size_t)(((t - 1) & 1) * 16384)
                                      + (p * 8) * 512 + L * 8;
            __builtin_amdgcn_s_setprio(1);
            #pragma unroll
            for (int ct = 0; ct < 8; ++ct) {
                half8 v0 = *(const half8*)(vb + (size_t)(ct * 512));
                half8 v1 = *(const half8*)(vb + (size_t)((16 + ct) * 512));
                acc[ct] = __builtin_amdgcn_mfma_f32_32x32x16_f16(v0, pk0p, acc[ct], 0, 0, 0);
                acc[ct] = __builtin_amdgcn_mfma_f32_32x32x16_f16(v1, pk1p, acc[ct], 0, 0, 0);
            }
            __builtin_amdgcn_s_setprio(0);
        }

        // ---- softmax(t): tree row-max (depth 4), permlane halves-combine ----
        float red[8];
        #pragma unroll
        for (int k = 0; k < 8; ++k) red[k] = fmaxf(so[k], so[k + 8]);
        #pragma unroll
        for (int k = 0; k < 4; ++k) red[k] = fmaxf(red[k], red[k + 4]);
        float tm = fmaxf(fmaxf(red[0], red[1]), fmaxf(red[2], red[3]));
        {
            unsigned int x, y;
            plswap(__builtin_bit_cast(unsigned int, tm),
                   __builtin_bit_cast(unsigned int, tm), x, y);
            tm = fmaxf(__builtin_bit_cast(float, x), __builtin_bit_cast(float, y));
        }

        // defer-max (T13): only bump running max when growth > 8 -> rescale rare
        const bool bump = tm > mo + 8.0f;
        const float mn = bump ? tm : mo;
        const float alpha = bump ? __expf(mo - mn) : 1.0f;
        mo = mn;

        float pvE[16];
        #pragma unroll
        for (int k = 0; k < 16; ++k) pvE[k] = __expf(so[k] - mn);
        // tree row-sum (depth 4)
        float sr[8];
        #pragma unroll
        for (int k = 0; k < 8; ++k) sr[k] = pvE[k] + pvE[k + 8];
        #pragma unroll
        for (int k = 0; k < 4; ++k) sr[k] = sr[k] + sr[k + 4];
        float ts = (sr[0] + sr[1]) + (sr[2] + sr[3]);
        {
            unsigned int x, y;
            plswap(__builtin_bit_cast(unsigned int, ts),
                   __builtin_bit_cast(unsigned int, ts), x, y);
            ts = __builtin_bit_cast(float, x) + __builtin_bit_cast(float, y);
        }
        l = l * alpha + ts;

        // ---- pack P; assemble BOTH B-frags via 4 permlane32_swap (no DS) ----
        unsigned int wd[8];
        #pragma unroll
        for (int i = 0; i < 8; ++i) wd[i] = pkrtz_u32(pvE[2*i], pvE[2*i+1]);
        unsigned int x0, y0, x1, y1, x2, y2, x3, y3;
        plswap(wd[0], wd[2], x0, y0);
        plswap(wd[1], wd[3], x1, y1);
        plswap(wd[4], wd[6], x2, y2);
        plswap(wd[5], wd[7], x3, y3);
        const uint4 pk0u = make_uint4(x0, x1, y0, y1);
        const uint4 pk1u = make_uint4(x2, x3, y2, y3);
        pk0p = __builtin_bit_cast(half8, pk0u);
        pk1p = __builtin_bit_cast(half8, pk1u);
        aprev = alpha;
        bprev = bump;
    }

    // ---- tail: drain all DMA (V(63) + dummy K), then PV(63) from bufV[1] ----
    asm volatile("s_waitcnt vmcnt(0)" ::: "memory");
    __builtin_amdgcn_s_barrier();
    asm volatile("" ::: "memory");
    {
        if (__ballot(bprev)) {
            #pragma unroll
            for (int i = 0; i < 8; ++i) {
                #pragma unroll
                for (int k = 0; k < 16; ++k) acc[i][k] *= aprev;
            }
        }
        const _Float16* vb = Vlds + (size_t)16384 + (p * 8) * 512 + L * 8;
        #pragma unroll
        for (int ct = 0; ct < 8; ++ct) {
            half8 v0 = *(const half8*)(vb + (size_t)(ct * 512));
            half8 v1 = *(const half8*)(vb + (size_t)((16 + ct) * 512));
            acc[ct] = __builtin_amdgcn_mfma_f32_32x32x16_f16(v0, pk0p, acc[ct], 0, 0, 0);
            acc[ct] = __builtin_amdgcn_mfma_f32_32x32x16_f16(v1, pk1p, acc[ct], 0, 0, 0);
        }
    }

    // ---- epilogue: scale by 1/l, direct coalesced stores (col = n = lane) ----
    const float invl = 1.0f / l;
    const size_t ob = ((size_t)b << 21) + (size_t)(nb + rg * 32 + r);
    #pragma unroll
    for (int ct = 0; ct < 8; ++ct) {
        const int cbase = p * 256 + ct * 32 + 4 * h;
        #pragma unroll
        for (int k = 0; k < 16; ++k) {
            int cl = (k & 3) + 8 * (k >> 2);
            out[ob + ((size_t)(cbase + cl) << 12)] = acc[ct][k] * invl;
        }
    }
}

extern "C" void kernel_launch(void* const* d_in, const int* in_sizes, int n_in,
                              void* d_out, int out_size, void* d_ws, size_t ws_size,
                              hipStream_t stream) {
    (void)in_sizes; (void)n_in; (void)out_size; (void)ws_size;
    const float* feat = (const float*)d_in[0];
    const float* mem  = (const float*)d_in[1];
    float* outp = (float*)d_out;
    _Float16* Ktile = (_Float16*)d_ws;                        // 2 MB
    _Float16* Vtile = Ktile + (size_t)2048 * 512;             // 2 MB

    static bool attr_done = false;
    if (!attr_done) {
        (void)hipFuncSetAttribute(reinterpret_cast<const void*>(attn_kernel),
                                  hipFuncAttributeMaxDynamicSharedMemorySize, SMEM_BYTES);
        attr_done = true;
    }

    hipLaunchKernelGGL(prep_kernel, dim3(64), dim3(256), 0, stream, mem, Ktile, Vtile);
    hipLaunchKernelGGL(attn_kernel, dim3(512), dim3(512), SMEM_BYTES, stream,
                       feat, Ktile, Vtile, outp);
}